// Round 7
// baseline (43.369 us; speedup 1.0000x reference)
//
#include <hip/hip_runtime.h>
#include <hip/hip_bf16.h>
#include <math.h>

#define NPC   2048          // points per cloud
#define NC    8             // clouds
#define NTOT  (NPC * NC)    // 16384
#define KMAX  32
#define R2    0.04f         // f32(0.04) — boundary-exact vs numpy's f64 compare

typedef short bf16x8  __attribute__((ext_vector_type(8)));
typedef float f32x16  __attribute__((ext_vector_type(16)));

// f32 -> bf16 round-to-nearest-even (finite values only)
__device__ __forceinline__ unsigned int f2bf(float f) {
    unsigned int u = __float_as_uint(f);
    return (u + 0x7FFFu + ((u >> 16) & 1u)) >> 16;
}

// packed f32x2 -> bf16x2 (RNE), src0 in LOW half (validated round 5)
__device__ __forceinline__ unsigned int pkbf(float a, float b) {
    unsigned int r;
    asm("v_cvt_pk_bf16_f32 %0, %1, %2" : "=v"(r) : "v"(a), "v"(b));
    return r;
}

// ---- half-swap epilogue (validated rounds 5/6): swapped C^T accum -> relu -> bf16 operand frags ----
// in:  a0/a1 hold C^T[ch = t*32 + (reg&3)+8*(reg>>2)+4*hi][e]   (bias already included)
// out: bout[kk] = relu(C)[e][ch = kk*16 + hi*8 + j]  (usable as A- or B-operand frag)
__device__ __forceinline__ void epi_swap(const f32x16& a0, const f32x16& a1,
                                         int hi, bf16x8 bout[4]) {
    unsigned int w_own[2][4][2];
    #pragma unroll
    for (int g = 0; g < 4; ++g) {
        w_own[0][g][0] = pkbf(fmaxf(a0[4*g+0],0.f), fmaxf(a0[4*g+1],0.f));
        w_own[0][g][1] = pkbf(fmaxf(a0[4*g+2],0.f), fmaxf(a0[4*g+3],0.f));
        w_own[1][g][0] = pkbf(fmaxf(a1[4*g+0],0.f), fmaxf(a1[4*g+1],0.f));
        w_own[1][g][1] = pkbf(fmaxf(a1[4*g+2],0.f), fmaxf(a1[4*g+3],0.f));
    }
    unsigned int R[2][2][2];
    #pragma unroll
    for (int t = 0; t < 2; ++t)
        #pragma unroll
        for (int gg = 0; gg < 2; ++gg)
            #pragma unroll
            for (int u = 0; u < 2; ++u) {
                unsigned int send = hi ? w_own[t][2*gg][u] : w_own[t][2*gg+1][u];
                R[t][gg][u] = (unsigned int)__shfl_xor((int)send, 32);
            }
    #pragma unroll
    for (int kk = 0; kk < 4; ++kk) {
        int t = kk >> 1;
        unsigned int O0 = hi ? w_own[t][(2*kk+1)&3][0] : w_own[t][(2*kk)&3][0];
        unsigned int O1 = hi ? w_own[t][(2*kk+1)&3][1] : w_own[t][(2*kk)&3][1];
        unsigned int R0 = R[t][kk&1][0], R1 = R[t][kk&1][1];
        int4 w;
        w.x = (int)(hi ? R0 : O0);
        w.y = (int)(hi ? R1 : O1);
        w.z = (int)(hi ? O0 : R0);
        w.w = (int)(hi ? O1 : R1);
        bout[kk] = __builtin_bit_cast(bf16x8, w);
    }
}

// ============ kernel 1: nbr search + xp pack + weight frags + tail copies (validated round 6) ============
__global__ __launch_bounds__(256) void prep_kernel(
    const float* __restrict__ x, const float* __restrict__ pos,
    const int* __restrict__ batch,
    const float* __restrict__ W1, const float* __restrict__ b1,
    const float* __restrict__ W2, const float* __restrict__ b2,
    const float* __restrict__ W3,
    int* __restrict__ nbr, int* __restrict__ cnts,
    float* __restrict__ xp, unsigned short* __restrict__ wf,
    float* __restrict__ out)
{
    int b = blockIdx.x, tid = threadIdx.x;
    if (b < 4096) {
        // ---- radius query: one wave per query; 256-pt groups, early-exit per group ----
        int q    = b * 4 + (tid >> 6);
        int lane = tid & 63;
        int base = (q >> 11) << 11;
        float qx = pos[3*q], qy = pos[3*q+1], qz = pos[3*q+2];
        int cnt = 0;
        for (int j0 = 0; j0 < NPC && cnt < KMAX; j0 += 256) {
            unsigned long long ms[4];
            bool vs[4];
            #pragma unroll
            for (int s = 0; s < 4; ++s) {
                int j = base + j0 + s*64 + lane;
                float dx = __fsub_rn(pos[3*j],   qx);
                float dy = __fsub_rn(pos[3*j+1], qy);
                float dz = __fsub_rn(pos[3*j+2], qz);
                float d2 = __fadd_rn(__fadd_rn(__fmul_rn(dx,dx), __fmul_rn(dy,dy)),
                                     __fmul_rn(dz,dz));
                vs[s] = d2 <= R2;
                ms[s] = __ballot(vs[s]);
            }
            #pragma unroll
            for (int s = 0; s < 4; ++s) {
                int before = (int)__popcll(ms[s] & ((1ull << lane) - 1ull));
                int slot = cnt + before;
                if (vs[s] && slot < KMAX) nbr[(q << 5) + slot] = base + j0 + s*64 + lane;
                cnt += (int)__popcll(ms[s]);
            }
        }
        if (lane == 0) cnts[q] = cnt < KMAX ? cnt : KMAX;
    } else if (b < 4160) {
        // ---- xp pack: {x0,x1,x2,p0,p1,p2,0,0} per point (32B records) ----
        int i = (b - 4096) * 256 + tid;
        float4 v0 = {x[3*i], x[3*i+1], x[3*i+2], pos[3*i]};
        float4 v1 = {pos[3*i+1], pos[3*i+2], 0.f, 0.f};
        float4* dst = (float4*)(xp + 8 * i);
        dst[0] = v0; dst[1] = v1;
    } else if (b < 4216) {
        // ---- weight fragments, contiguous: wg1a[1024] | wg2a[5120] | wg3b[8192] ushorts ----
        int g = (b - 4160) * 256 + tid;       // 0..14335
        if (g < 1024) {
            int j = g & 7, lane = (g >> 3) & 63, t = g >> 9;
            int k = (lane >> 5)*8 + j, ch = t*32 + (lane & 31);
            float v = (k < 6) ? W1[k*64 + ch] : (k == 6 ? b1[ch] : 0.f);
            wf[g] = (unsigned short)f2bf(v);
        } else if (g < 6144) {
            int g2 = g - 1024;
            int j = g2 & 7, lane = (g2 >> 3) & 63, f = g2 >> 9;
            int t = f / 5, kk = f % 5;
            int k = kk*16 + (lane >> 5)*8 + j, row = t*32 + (lane & 31);
            float v = 0.f;
            if (k < 64)       v = W2[k*64 + row];
            else if (k == 64) v = b2[row];
            wf[g] = (unsigned short)f2bf(v);
        } else {
            int g3 = g - 6144;
            int j = g3 & 7, lane = (g3 >> 3) & 63, f = g3 >> 9;
            int n = f >> 2, kk = f & 3;
            int k = kk*16 + (lane >> 5)*8 + j, col = n*32 + (lane & 31);
            wf[g] = (unsigned short)f2bf(W3[k*128 + col]);
        }
    } else {
        // ---- tail copies: pos + batch into output tuple ----
        int i = (b - 4216) * 256 + tid;
        if (i < NTOT*3) out[NTOT*128 + i] = pos[i];
        if (i < NTOT)   out[NTOT*131 + i] = (float)batch[i];
    }
}

// ============ kernel 2: fused MLP, all-MFMA, weights in VGPRs, Q=8 queries/wave ============
__global__ __launch_bounds__(256, 2) void mlp_kernel(
    const unsigned short* __restrict__ wf, const float* __restrict__ b3,
    const float* __restrict__ xp,
    const int* __restrict__ nbr, const int* __restrict__ cnts,
    float* __restrict__ out)
{
    const int tid  = threadIdx.x;
    const int lane = tid & 63, wave = tid >> 6;
    const int e = lane & 31, hi = lane >> 5;

    // ---- all weight fragments resident in VGPRs (loaded once; wf is L2-resident) ----
    bf16x8 wA1[2], wA2[10], wB3[16];
    #pragma unroll
    for (int t = 0; t < 2; ++t)
        wA1[t] = *(const bf16x8*)(wf + (t*64 + lane)*8);
    #pragma unroll
    for (int f = 0; f < 10; ++f)
        wA2[f] = *(const bf16x8*)(wf + 1024 + (f*64 + lane)*8);
    #pragma unroll
    for (int f = 0; f < 16; ++f)
        wB3[f] = *(const bf16x8*)(wf + 6144 + (f*64 + lane)*8);

    const unsigned int one_w = pkbf(1.0f, 0.0f);
    int4 ow = {0,0,0,0};
    if (!hi) ow.x = (int)one_w;
    const bf16x8 onef = __builtin_bit_cast(bf16x8, ow);   // GEMM2 bias-row B-frag

    float b3v[4];
    #pragma unroll
    for (int n = 0; n < 4; ++n) b3v[n] = b3[n*32 + e];

    const int qbase = __builtin_amdgcn_readfirstlane(blockIdx.x * 32 + wave * 8);

    // ---- hoisted gather state for all 8 queries (issued together, latency overlapped) ----
    int cnt8[8], nbrv[8];
    float qpx[8], qpy[8], qpz[8];
    #pragma unroll
    for (int i = 0; i < 8; ++i) {
        cnt8[i] = cnts[qbase + i];                       // wave-uniform -> scalar loads
        nbrv[i] = nbr[((qbase + i) << 5) + e];           // per-lane, 8 outstanding
        qpx[i] = xp[8*(qbase+i) + 3];
        qpy[i] = xp[8*(qbase+i) + 4];
        qpz[i] = xp[8*(qbase+i) + 5];
    }

    // prefetch query 0's neighbor record
    int jg0 = (e < cnt8[0]) ? nbrv[0] : qbase;
    float4 xj0 = ((const float4*)(xp + 8*jg0))[0];
    float4 xj1 = ((const float4*)(xp + 8*jg0))[1];

    #pragma unroll
    for (int i = 0; i < 8; ++i) {
        const int cnt = cnt8[i];
        const int qq  = qbase + i;
        float4 cj0 = xj0, cj1 = xj1;
        if (i < 7) {   // prefetch next query's neighbor record under this query's compute
            int jgn = (e < cnt8[i+1]) ? nbrv[i+1] : (qbase + i + 1);
            xj0 = ((const float4*)(xp + 8*jgn))[0];
            xj1 = ((const float4*)(xp + 8*jgn))[1];
        }

        float r0 = cj0.w - qpx[i], r1 = cj1.x - qpy[i], r2 = cj1.y - qpz[i];

        // ---- layer1 msg B-frag: k = [x0 x1 x2 r0 r1 r2 1 0 | 0...] ----
        int4 mw;
        mw.x = hi ? 0 : (int)pkbf(cj0.x, cj0.y);
        mw.y = hi ? 0 : (int)pkbf(cj0.z, r0);
        mw.z = hi ? 0 : (int)pkbf(r1, r2);
        mw.w = hi ? 0 : (int)one_w;
        bf16x8 msgf = __builtin_bit_cast(bf16x8, mw);

        // ---- layer1 (swapped): C1^T[64 ch][32 e], K=16 ----
        f32x16 acc0 = {}, acc1 = {};
        acc0 = __builtin_amdgcn_mfma_f32_32x32x16_bf16(wA1[0], msgf, acc0, 0, 0, 0);
        acc1 = __builtin_amdgcn_mfma_f32_32x32x16_bf16(wA1[1], msgf, acc1, 0, 0, 0);
        bf16x8 h1f[4];
        epi_swap(acc0, acc1, hi, h1f);

        // ---- GEMM2 (swapped): C2^T[64][32], K=80 (bias row k=64) ----
        f32x16 c20 = {}, c21 = {};
        #pragma unroll
        for (int kk = 0; kk < 4; ++kk) {
            c20 = __builtin_amdgcn_mfma_f32_32x32x16_bf16(wA2[kk],     h1f[kk], c20, 0, 0, 0);
            c21 = __builtin_amdgcn_mfma_f32_32x32x16_bf16(wA2[5 + kk], h1f[kk], c21, 0, 0, 0);
        }
        c20 = __builtin_amdgcn_mfma_f32_32x32x16_bf16(wA2[4], onef, c20, 0, 0, 0);
        c21 = __builtin_amdgcn_mfma_f32_32x32x16_bf16(wA2[9], onef, c21, 0, 0, 0);
        bf16x8 h2f[4];
        epi_swap(c20, c21, hi, h2f);

        // ---- GEMM3 (non-swapped): C[32 e][128 out] + fused max over edges ----
        const bool full = (cnt == 32);   // wave-uniform scalar branch
        #pragma unroll
        for (int n = 0; n < 4; ++n) {
            f32x16 c = {};
            #pragma unroll
            for (int kk = 0; kk < 4; ++kk)
                c = __builtin_amdgcn_mfma_f32_32x32x16_bf16(h2f[kk], wB3[n*4 + kk], c, 0, 0, 0);
            float m;
            if (full) {
                m = fmaxf(fmaxf(fmaxf(c[0],c[1]), fmaxf(c[2],c[3])),
                          fmaxf(fmaxf(c[4],c[5]), fmaxf(c[6],c[7])));
                m = fmaxf(m, fmaxf(fmaxf(c[8],c[9]),  fmaxf(c[10],c[11])));
                m = fmaxf(m, fmaxf(fmaxf(c[12],c[13]), fmaxf(c[14],c[15])));
            } else {
                m = -INFINITY;
                #pragma unroll
                for (int reg = 0; reg < 16; ++reg) {
                    int r = (reg & 3) + 8*(reg >> 2) + 4*hi;   // edge slot
                    float v = (r < cnt) ? c[reg] : -INFINITY;
                    m = fmaxf(m, v);
                }
            }
            m = fmaxf(m, __shfl_xor(m, 32));
            m += b3v[n];
            if (hi == 0) out[qq*128 + n*32 + e] = m;
        }
    }
}

extern "C" void kernel_launch(void* const* d_in, const int* in_sizes, int n_in,
                              void* d_out, int out_size, void* d_ws, size_t ws_size,
                              hipStream_t stream) {
    const float* x     = (const float*)d_in[0];
    const float* pos   = (const float*)d_in[1];
    const int*   batch = (const int*)d_in[2];
    const float* W1    = (const float*)d_in[3];
    const float* b1    = (const float*)d_in[4];
    const float* W2    = (const float*)d_in[5];
    const float* b2    = (const float*)d_in[6];
    const float* W3    = (const float*)d_in[7];
    const float* b3    = (const float*)d_in[8];
    float* out = (float*)d_out;

    int* nbr  = (int*)d_ws;                                  // 16384*32 int  (2 MB)
    int* cnts = nbr + NTOT * KMAX;                           // 16384 int     (64 KB)
    float* xp = (float*)(cnts + NTOT);                       // 16384*8 f32   (512 KB)
    unsigned short* wfrag = (unsigned short*)(xp + NTOT*8);  // 14336 bf16    (28 KB)

    prep_kernel<<<4408, 256, 0, stream>>>(x, pos, batch, W1, b1, W2, b2, W3,
                                          nbr, cnts, xp, wfrag, out);
    mlp_kernel<<<NTOT / 32, 256, 0, stream>>>(wfrag, b3, xp, nbr, cnts, out);
}

// Round 8
// 40.731 us; speedup vs baseline: 1.0648x; 1.0648x over previous
//
#include <hip/hip_runtime.h>
#include <hip/hip_bf16.h>
#include <math.h>

#define NPC   2048          // points per cloud
#define NC    8             // clouds
#define NTOT  (NPC * NC)    // 16384
#define KMAX  32
#define R2    0.04f         // f32(0.04) — boundary-exact vs numpy's f64 compare

typedef short bf16x8  __attribute__((ext_vector_type(8)));
typedef float f32x16  __attribute__((ext_vector_type(16)));

// f32 -> bf16 round-to-nearest-even (finite values only)
__device__ __forceinline__ unsigned int f2bf(float f) {
    unsigned int u = __float_as_uint(f);
    return (u + 0x7FFFu + ((u >> 16) & 1u)) >> 16;
}

// packed f32x2 -> bf16x2 (RNE), src0 in LOW half (validated round 5)
__device__ __forceinline__ unsigned int pkbf(float a, float b) {
    unsigned int r;
    asm("v_cvt_pk_bf16_f32 %0, %1, %2" : "=v"(r) : "v"(a), "v"(b));
    return r;
}

// ---- k-permuted epilogue: relu+pack 8 consecutive acc regs into an operand frag ----
// Valid because prep permutes the NEXT layer's weight k-rows by
// P(kk,hi,j) = (j&3) + 4*hi + 8*(2*(kk&1)+(j>>2)) + 32*(kk>>1), which equals the
// 32x32 accumulator's natural per-lane row order: frag[kk] elem j = acc_{kk>>1}[8*(kk&1)+j].
__device__ __forceinline__ bf16x8 mk_frag(const f32x16& a, int off) {  // off: 0 or 8 (compile-time)
    int4 w;
    w.x = (int)pkbf(fmaxf(a[off+0],0.f), fmaxf(a[off+1],0.f));
    w.y = (int)pkbf(fmaxf(a[off+2],0.f), fmaxf(a[off+3],0.f));
    w.z = (int)pkbf(fmaxf(a[off+4],0.f), fmaxf(a[off+5],0.f));
    w.w = (int)pkbf(fmaxf(a[off+6],0.f), fmaxf(a[off+7],0.f));
    return __builtin_bit_cast(bf16x8, w);
}

// ============ kernel 1: nbr search + xp pack + weight frags (k-permuted) + tail copies ============
__global__ __launch_bounds__(256) void prep_kernel(
    const float* __restrict__ x, const float* __restrict__ pos,
    const int* __restrict__ batch,
    const float* __restrict__ W1, const float* __restrict__ b1,
    const float* __restrict__ W2, const float* __restrict__ b2,
    const float* __restrict__ W3,
    int* __restrict__ nbr, int* __restrict__ cnts,
    float* __restrict__ xp, unsigned short* __restrict__ wf,
    float* __restrict__ out)
{
    int b = blockIdx.x, tid = threadIdx.x;
    if (b < 4096) {
        // ---- radius query: one wave per query; 256-pt groups, early-exit per group ----
        int q    = b * 4 + (tid >> 6);
        int lane = tid & 63;
        int base = (q >> 11) << 11;
        float qx = pos[3*q], qy = pos[3*q+1], qz = pos[3*q+2];
        int cnt = 0;
        for (int j0 = 0; j0 < NPC && cnt < KMAX; j0 += 256) {
            unsigned long long ms[4];
            bool vs[4];
            #pragma unroll
            for (int s = 0; s < 4; ++s) {
                int j = base + j0 + s*64 + lane;
                float dx = __fsub_rn(pos[3*j],   qx);
                float dy = __fsub_rn(pos[3*j+1], qy);
                float dz = __fsub_rn(pos[3*j+2], qz);
                float d2 = __fadd_rn(__fadd_rn(__fmul_rn(dx,dx), __fmul_rn(dy,dy)),
                                     __fmul_rn(dz,dz));
                vs[s] = d2 <= R2;
                ms[s] = __ballot(vs[s]);
            }
            #pragma unroll
            for (int s = 0; s < 4; ++s) {
                int before = (int)__popcll(ms[s] & ((1ull << lane) - 1ull));
                int slot = cnt + before;
                if (vs[s] && slot < KMAX) nbr[(q << 5) + slot] = base + j0 + s*64 + lane;
                cnt += (int)__popcll(ms[s]);
            }
        }
        if (lane == 0) cnts[q] = cnt < KMAX ? cnt : KMAX;
    } else if (b < 4160) {
        // ---- xp pack: {x0,x1,x2,p0,p1,p2,0,0} per point (32B records) ----
        int i = (b - 4096) * 256 + tid;
        float4 v0 = {x[3*i], x[3*i+1], x[3*i+2], pos[3*i]};
        float4 v1 = {pos[3*i+1], pos[3*i+2], 0.f, 0.f};
        float4* dst = (float4*)(xp + 8 * i);
        dst[0] = v0; dst[1] = v1;
    } else if (b < 4216) {
        // ---- weight fragments: wg1a[1024] | wg2a[5120] | wg3b[8192] ushorts ----
        // wg2a (kk<4) and wg3b use k-permutation P so the MLP epilogue is shuffle-free.
        int g = (b - 4160) * 256 + tid;       // 0..14335
        if (g < 1024) {
            // layer1 A = W1^T padded K=16, bias at k=6 (natural k order)
            int j = g & 7, lane = (g >> 3) & 63, t = g >> 9;
            int k = (lane >> 5)*8 + j, ch = t*32 + (lane & 31);
            float v = (k < 6) ? W1[k*64 + ch] : (k == 6 ? b1[ch] : 0.f);
            wf[g] = (unsigned short)f2bf(v);
        } else if (g < 6144) {
            // GEMM2 A = W2^T (K=80, bias row at logical k=64); k-rows permuted by P
            int g2 = g - 1024;
            int j = g2 & 7, lane = (g2 >> 3) & 63, f = g2 >> 9;
            int t = f / 5, kk = f % 5;
            int hi = lane >> 5, row = t*32 + (lane & 31);
            float v;
            if (kk < 4) {
                int k = (j & 3) + 4*hi + 8*(2*(kk & 1) + (j >> 2)) + 32*(kk >> 1);
                v = W2[k*64 + row];
            } else {
                v = (hi == 0 && j == 0) ? b2[row] : 0.f;   // bias row, matches `onef` B-frag
            }
            wf[g] = (unsigned short)f2bf(v);
        } else {
            // GEMM3 B = W3 (K=64); k-rows permuted by P
            int g3 = g - 6144;
            int j = g3 & 7, lane = (g3 >> 3) & 63, f = g3 >> 9;
            int n = f >> 2, kk = f & 3;
            int hi = lane >> 5, col = n*32 + (lane & 31);
            int k = (j & 3) + 4*hi + 8*(2*(kk & 1) + (j >> 2)) + 32*(kk >> 1);
            wf[g] = (unsigned short)f2bf(W3[k*128 + col]);
        }
    } else {
        // ---- tail copies: pos + batch into output tuple ----
        int i = (b - 4216) * 256 + tid;
        if (i < NTOT*3) out[NTOT*128 + i] = pos[i];
        if (i < NTOT)   out[NTOT*131 + i] = (float)batch[i];
    }
}

// ============ kernel 2: fused MLP, all-MFMA, LDS weights, shuffle-free epilogues, Q=1/wave ============
__global__ __launch_bounds__(256, 4) void mlp_kernel(
    const unsigned short* __restrict__ wf, const float* __restrict__ b3,
    const float* __restrict__ xp,
    const int* __restrict__ nbr, const int* __restrict__ cnts,
    float* __restrict__ out)
{
    __shared__ int4 sW[1664];   // 26624B: wg2a(640 int4) | wg3b(1024 int4)

    const int tid  = threadIdx.x;
    const int lane = tid & 63, wave = tid >> 6;
    const int e = lane & 31, hi = lane >> 5;

    const int qq  = __builtin_amdgcn_readfirstlane(blockIdx.x * 4 + wave);
    const int cnt = cnts[qq];

    // issue gather loads early (overlap with staging)
    int jg = (e < cnt) ? nbr[(qq << 5) + e] : qq;
    const float4* pj = (const float4*)(xp + 8*jg);
    float4 xj0 = pj[0], xj1 = pj[1];
    float qpx = xp[8*qq + 3], qpy = xp[8*qq + 4], qpz = xp[8*qq + 5];

    // layer1 W frags in registers (tiny, used first)
    bf16x8 wA1_0 = *(const bf16x8*)(wf + (0*64 + lane)*8);
    bf16x8 wA1_1 = *(const bf16x8*)(wf + (1*64 + lane)*8);

    float b3v[4];
    #pragma unroll
    for (int n = 0; n < 4; ++n) b3v[n] = b3[n*32 + e];

    // stage GEMM2/GEMM3 weight frags to LDS (once per block)
    const int4* wsrc = (const int4*)(wf + 1024);
    #pragma unroll
    for (int it = 0; it < 7; ++it) {
        int idx = it*256 + tid;
        if (idx < 1664) sW[idx] = wsrc[idx];
    }
    __syncthreads();

    const unsigned int one_w = pkbf(1.0f, 0.0f);
    int4 ow = {0,0,0,0};
    if (!hi) ow.x = (int)one_w;
    const bf16x8 onef = __builtin_bit_cast(bf16x8, ow);   // GEMM2 bias-row B-frag

    // ---- layer1 msg B-frag: k = [x0 x1 x2 r0 r1 r2 1 0 | 0...] ----
    float r0 = xj0.w - qpx, r1 = xj1.x - qpy, r2 = xj1.y - qpz;
    int4 mw;
    mw.x = hi ? 0 : (int)pkbf(xj0.x, xj0.y);
    mw.y = hi ? 0 : (int)pkbf(xj0.z, r0);
    mw.z = hi ? 0 : (int)pkbf(r1, r2);
    mw.w = hi ? 0 : (int)one_w;
    bf16x8 msgf = __builtin_bit_cast(bf16x8, mw);

    // ---- layer1 (swapped): C1^T[64 ch][32 e], K=16 ----
    f32x16 acc0 = {}, acc1 = {};
    acc0 = __builtin_amdgcn_mfma_f32_32x32x16_bf16(wA1_0, msgf, acc0, 0, 0, 0);
    acc1 = __builtin_amdgcn_mfma_f32_32x32x16_bf16(wA1_1, msgf, acc1, 0, 0, 0);
    bf16x8 h1f[4];
    h1f[0] = mk_frag(acc0, 0);
    h1f[1] = mk_frag(acc0, 8);
    h1f[2] = mk_frag(acc1, 0);
    h1f[3] = mk_frag(acc1, 8);

    // ---- GEMM2 (swapped): C2^T[64][32], K=80 (bias row via onef) ----
    f32x16 c20 = {}, c21 = {};
    #pragma unroll
    for (int kk = 0; kk < 4; ++kk) {
        c20 = __builtin_amdgcn_mfma_f32_32x32x16_bf16(
                *(const bf16x8*)&sW[(0*5 + kk)*64 + lane], h1f[kk], c20, 0, 0, 0);
        c21 = __builtin_amdgcn_mfma_f32_32x32x16_bf16(
                *(const bf16x8*)&sW[(1*5 + kk)*64 + lane], h1f[kk], c21, 0, 0, 0);
    }
    c20 = __builtin_amdgcn_mfma_f32_32x32x16_bf16(
            *(const bf16x8*)&sW[(0*5 + 4)*64 + lane], onef, c20, 0, 0, 0);
    c21 = __builtin_amdgcn_mfma_f32_32x32x16_bf16(
            *(const bf16x8*)&sW[(1*5 + 4)*64 + lane], onef, c21, 0, 0, 0);
    bf16x8 h2f[4];
    h2f[0] = mk_frag(c20, 0);
    h2f[1] = mk_frag(c20, 8);
    h2f[2] = mk_frag(c21, 0);
    h2f[3] = mk_frag(c21, 8);

    // ---- GEMM3 (non-swapped): C[32 e][128 out] + fused max over edges ----
    const bool full = (cnt == 32);   // wave-uniform scalar branch
    #pragma unroll
    for (int n = 0; n < 4; ++n) {
        f32x16 c = {};
        #pragma unroll
        for (int kk = 0; kk < 4; ++kk)
            c = __builtin_amdgcn_mfma_f32_32x32x16_bf16(
                    h2f[kk], *(const bf16x8*)&sW[640 + (n*4 + kk)*64 + lane], c, 0, 0, 0);
        float m;
        if (full) {
            m = fmaxf(fmaxf(fmaxf(c[0],c[1]), fmaxf(c[2],c[3])),
                      fmaxf(fmaxf(c[4],c[5]), fmaxf(c[6],c[7])));
            m = fmaxf(m, fmaxf(fmaxf(c[8],c[9]),  fmaxf(c[10],c[11])));
            m = fmaxf(m, fmaxf(fmaxf(c[12],c[13]), fmaxf(c[14],c[15])));
        } else {
            m = -INFINITY;
            #pragma unroll
            for (int reg = 0; reg < 16; ++reg) {
                int r = (reg & 3) + 8*(reg >> 2) + 4*hi;   // edge slot
                float v = (r < cnt) ? c[reg] : -INFINITY;
                m = fmaxf(m, v);
            }
        }
        m = fmaxf(m, __shfl_xor(m, 32));
        m += b3v[n];
        if (hi == 0) out[qq*128 + n*32 + (lane & 31)] = m;
    }
}

extern "C" void kernel_launch(void* const* d_in, const int* in_sizes, int n_in,
                              void* d_out, int out_size, void* d_ws, size_t ws_size,
                              hipStream_t stream) {
    const float* x     = (const float*)d_in[0];
    const float* pos   = (const float*)d_in[1];
    const int*   batch = (const int*)d_in[2];
    const float* W1    = (const float*)d_in[3];
    const float* b1    = (const float*)d_in[4];
    const float* W2    = (const float*)d_in[5];
    const float* b2    = (const float*)d_in[6];
    const float* W3    = (const float*)d_in[7];
    const float* b3    = (const float*)d_in[8];
    float* out = (float*)d_out;

    int* nbr  = (int*)d_ws;                                  // 16384*32 int  (2 MB)
    int* cnts = nbr + NTOT * KMAX;                           // 16384 int     (64 KB)
    float* xp = (float*)(cnts + NTOT);                       // 16384*8 f32   (512 KB)
    unsigned short* wfrag = (unsigned short*)(xp + NTOT*8);  // 14336 bf16    (28 KB)

    prep_kernel<<<4408, 256, 0, stream>>>(x, pos, batch, W1, b1, W2, b2, W3,
                                          nbr, cnts, xp, wfrag, out);
    mlp_kernel<<<NTOT / 4, 256, 0, stream>>>(wfrag, b3, xp, nbr, cnts, out);
}

// Round 9
// 38.445 us; speedup vs baseline: 1.1281x; 1.0595x over previous
//
#include <hip/hip_runtime.h>
#include <hip/hip_bf16.h>
#include <math.h>

#define NPC   2048          // points per cloud
#define NC    8             // clouds
#define NTOT  (NPC * NC)    // 16384
#define KMAX  32
#define R2    0.04f         // f32(0.04) — boundary-exact vs numpy's f64 compare

typedef short bf16x8  __attribute__((ext_vector_type(8)));
typedef float f32x16  __attribute__((ext_vector_type(16)));

// f32 -> bf16 round-to-nearest-even (finite values only)
__device__ __forceinline__ unsigned int f2bf(float f) {
    unsigned int u = __float_as_uint(f);
    return (u + 0x7FFFu + ((u >> 16) & 1u)) >> 16;
}

// packed f32x2 -> bf16x2 (RNE), src0 in LOW half (validated round 5)
__device__ __forceinline__ unsigned int pkbf(float a, float b) {
    unsigned int r;
    asm("v_cvt_pk_bf16_f32 %0, %1, %2" : "=v"(r) : "v"(a), "v"(b));
    return r;
}

// ---- k-permuted epilogue (validated round 8): relu+pack 8 consecutive acc regs -> operand frag ----
// Prep permutes the NEXT layer's weight k-rows by
// P(kk,hi,j) = (j&3) + 4*hi + 8*(2*(kk&1)+(j>>2)) + 32*(kk>>1)  == accumulator's natural row order.
__device__ __forceinline__ bf16x8 mk_frag(const f32x16& a, int off) {  // off: 0 or 8 (compile-time)
    int4 w;
    w.x = (int)pkbf(fmaxf(a[off+0],0.f), fmaxf(a[off+1],0.f));
    w.y = (int)pkbf(fmaxf(a[off+2],0.f), fmaxf(a[off+3],0.f));
    w.z = (int)pkbf(fmaxf(a[off+4],0.f), fmaxf(a[off+5],0.f));
    w.w = (int)pkbf(fmaxf(a[off+6],0.f), fmaxf(a[off+7],0.f));
    return __builtin_bit_cast(bf16x8, w);
}

// ============ kernel 1: LDS-staged nbr search + xp pack + weight frags + tail copies ============
// 512 threads/block. Blocks 0..2047: neighbor search, 8 queries/block, cloud pos staged in LDS.
__global__ __launch_bounds__(512) void prep_kernel(
    const float* __restrict__ x, const float* __restrict__ pos,
    const int* __restrict__ batch,
    const float* __restrict__ W1, const float* __restrict__ b1,
    const float* __restrict__ W2, const float* __restrict__ b2,
    const float* __restrict__ W3,
    int* __restrict__ nbr, int* __restrict__ cnts,
    float* __restrict__ xp, unsigned short* __restrict__ wf,
    float* __restrict__ out)
{
    __shared__ float4 sP[NPC];   // 32 KB: this cloud's positions (pad .w=0)

    int b = blockIdx.x, tid = threadIdx.x;
    if (b < 2048) {
        const int base = (b >> 8) << 11;      // cloud start (256 blocks per cloud)
        // ---- stage cloud positions into LDS once ----
        #pragma unroll
        for (int p = tid; p < NPC; p += 512) {
            sP[p] = make_float4(pos[3*(base+p)], pos[3*(base+p)+1], pos[3*(base+p)+2], 0.f);
        }
        __syncthreads();

        // ---- one wave per query; scan LDS in 256-pt groups, early-exit ----
        const int lane = tid & 63;
        const int q    = b * 8 + (tid >> 6);
        float qx = pos[3*q], qy = pos[3*q+1], qz = pos[3*q+2];
        int cnt = 0;
        for (int j0 = 0; j0 < NPC && cnt < KMAX; j0 += 256) {
            unsigned long long ms[4];
            bool vs[4];
            #pragma unroll
            for (int s = 0; s < 4; ++s) {
                float4 p = sP[j0 + s*64 + lane];          // ds_read_b128, imm offsets
                float dx = __fsub_rn(p.x, qx);
                float dy = __fsub_rn(p.y, qy);
                float dz = __fsub_rn(p.z, qz);
                float d2 = __fadd_rn(__fadd_rn(__fmul_rn(dx,dx), __fmul_rn(dy,dy)),
                                     __fmul_rn(dz,dz));
                vs[s] = d2 <= R2;
                ms[s] = __ballot(vs[s]);
            }
            #pragma unroll
            for (int s = 0; s < 4; ++s) {
                int before = (int)__popcll(ms[s] & ((1ull << lane) - 1ull));
                int slot = cnt + before;
                if (vs[s] && slot < KMAX) nbr[(q << 5) + slot] = base + j0 + s*64 + lane;
                cnt += (int)__popcll(ms[s]);
            }
        }
        if (lane == 0) cnts[q] = cnt < KMAX ? cnt : KMAX;
    } else if (b < 2080) {
        // ---- xp pack: {x0,x1,x2,p0,p1,p2,0,0} per point (32B records) ----
        int i = (b - 2048) * 512 + tid;
        float4 v0 = {x[3*i], x[3*i+1], x[3*i+2], pos[3*i]};
        float4 v1 = {pos[3*i+1], pos[3*i+2], 0.f, 0.f};
        float4* dst = (float4*)(xp + 8 * i);
        dst[0] = v0; dst[1] = v1;
    } else if (b < 2108) {
        // ---- weight fragments: wg1a[1024] | wg2a[5120] | wg3b[8192] ushorts (k-permuted) ----
        int g = (b - 2080) * 512 + tid;       // 0..14335
        if (g < 1024) {
            // layer1 A = W1^T padded K=16, bias at k=6 (natural k order)
            int j = g & 7, lane = (g >> 3) & 63, t = g >> 9;
            int k = (lane >> 5)*8 + j, ch = t*32 + (lane & 31);
            float v = (k < 6) ? W1[k*64 + ch] : (k == 6 ? b1[ch] : 0.f);
            wf[g] = (unsigned short)f2bf(v);
        } else if (g < 6144) {
            // GEMM2 A = W2^T (K=80, bias row at logical k=64); k-rows permuted by P
            int g2 = g - 1024;
            int j = g2 & 7, lane = (g2 >> 3) & 63, f = g2 >> 9;
            int t = f / 5, kk = f % 5;
            int hi = lane >> 5, row = t*32 + (lane & 31);
            float v;
            if (kk < 4) {
                int k = (j & 3) + 4*hi + 8*(2*(kk & 1) + (j >> 2)) + 32*(kk >> 1);
                v = W2[k*64 + row];
            } else {
                v = (hi == 0 && j == 0) ? b2[row] : 0.f;   // bias row, matches `onef` B-frag
            }
            wf[g] = (unsigned short)f2bf(v);
        } else {
            // GEMM3 B = W3 (K=64); k-rows permuted by P
            int g3 = g - 6144;
            int j = g3 & 7, lane = (g3 >> 3) & 63, f = g3 >> 9;
            int n = f >> 2, kk = f & 3;
            int hi = lane >> 5, col = n*32 + (lane & 31);
            int k = (j & 3) + 4*hi + 8*(2*(kk & 1) + (j >> 2)) + 32*(kk >> 1);
            wf[g] = (unsigned short)f2bf(W3[k*128 + col]);
        }
    } else {
        // ---- tail copies: pos + batch into output tuple ----
        int i = (b - 2108) * 512 + tid;
        if (i < NTOT*3) out[NTOT*128 + i] = pos[i];
        if (i < NTOT)   out[NTOT*131 + i] = (float)batch[i];
    }
}

// ============ kernel 2: fused MLP, all-MFMA, LDS weights, shuffle-free epilogues (round 8) ============
__global__ __launch_bounds__(256, 4) void mlp_kernel(
    const unsigned short* __restrict__ wf, const float* __restrict__ b3,
    const float* __restrict__ xp,
    const int* __restrict__ nbr, const int* __restrict__ cnts,
    float* __restrict__ out)
{
    __shared__ int4 sW[1664];   // 26624B: wg2a(640 int4) | wg3b(1024 int4)

    const int tid  = threadIdx.x;
    const int lane = tid & 63, wave = tid >> 6;
    const int e = lane & 31, hi = lane >> 5;

    const int qq  = __builtin_amdgcn_readfirstlane(blockIdx.x * 4 + wave);
    const int cnt = cnts[qq];

    // issue gather loads early (overlap with staging)
    int jg = (e < cnt) ? nbr[(qq << 5) + e] : qq;
    const float4* pj = (const float4*)(xp + 8*jg);
    float4 xj0 = pj[0], xj1 = pj[1];
    float qpx = xp[8*qq + 3], qpy = xp[8*qq + 4], qpz = xp[8*qq + 5];

    // layer1 W frags in registers (tiny, used first)
    bf16x8 wA1_0 = *(const bf16x8*)(wf + (0*64 + lane)*8);
    bf16x8 wA1_1 = *(const bf16x8*)(wf + (1*64 + lane)*8);

    float b3v[4];
    #pragma unroll
    for (int n = 0; n < 4; ++n) b3v[n] = b3[n*32 + e];

    // stage GEMM2/GEMM3 weight frags to LDS (once per block)
    const int4* wsrc = (const int4*)(wf + 1024);
    #pragma unroll
    for (int it = 0; it < 7; ++it) {
        int idx = it*256 + tid;
        if (idx < 1664) sW[idx] = wsrc[idx];
    }
    __syncthreads();

    const unsigned int one_w = pkbf(1.0f, 0.0f);
    int4 ow = {0,0,0,0};
    if (!hi) ow.x = (int)one_w;
    const bf16x8 onef = __builtin_bit_cast(bf16x8, ow);   // GEMM2 bias-row B-frag

    // ---- layer1 msg B-frag: k = [x0 x1 x2 r0 r1 r2 1 0 | 0...] ----
    float r0 = xj0.w - qpx, r1 = xj1.x - qpy, r2 = xj1.y - qpz;
    int4 mw;
    mw.x = hi ? 0 : (int)pkbf(xj0.x, xj0.y);
    mw.y = hi ? 0 : (int)pkbf(xj0.z, r0);
    mw.z = hi ? 0 : (int)pkbf(r1, r2);
    mw.w = hi ? 0 : (int)one_w;
    bf16x8 msgf = __builtin_bit_cast(bf16x8, mw);

    // ---- layer1 (swapped): C1^T[64 ch][32 e], K=16 ----
    f32x16 acc0 = {}, acc1 = {};
    acc0 = __builtin_amdgcn_mfma_f32_32x32x16_bf16(wA1_0, msgf, acc0, 0, 0, 0);
    acc1 = __builtin_amdgcn_mfma_f32_32x32x16_bf16(wA1_1, msgf, acc1, 0, 0, 0);
    bf16x8 h1f[4];
    h1f[0] = mk_frag(acc0, 0);
    h1f[1] = mk_frag(acc0, 8);
    h1f[2] = mk_frag(acc1, 0);
    h1f[3] = mk_frag(acc1, 8);

    // ---- GEMM2 (swapped): C2^T[64][32], K=80 (bias row via onef) ----
    f32x16 c20 = {}, c21 = {};
    #pragma unroll
    for (int kk = 0; kk < 4; ++kk) {
        c20 = __builtin_amdgcn_mfma_f32_32x32x16_bf16(
                *(const bf16x8*)&sW[(0*5 + kk)*64 + lane], h1f[kk], c20, 0, 0, 0);
        c21 = __builtin_amdgcn_mfma_f32_32x32x16_bf16(
                *(const bf16x8*)&sW[(1*5 + kk)*64 + lane], h1f[kk], c21, 0, 0, 0);
    }
    c20 = __builtin_amdgcn_mfma_f32_32x32x16_bf16(
            *(const bf16x8*)&sW[(0*5 + 4)*64 + lane], onef, c20, 0, 0, 0);
    c21 = __builtin_amdgcn_mfma_f32_32x32x16_bf16(
            *(const bf16x8*)&sW[(1*5 + 4)*64 + lane], onef, c21, 0, 0, 0);
    bf16x8 h2f[4];
    h2f[0] = mk_frag(c20, 0);
    h2f[1] = mk_frag(c20, 8);
    h2f[2] = mk_frag(c21, 0);
    h2f[3] = mk_frag(c21, 8);

    // ---- GEMM3 (non-swapped): C[32 e][128 out] + fused max over edges ----
    const bool full = (cnt == 32);   // wave-uniform scalar branch
    #pragma unroll
    for (int n = 0; n < 4; ++n) {
        f32x16 c = {};
        #pragma unroll
        for (int kk = 0; kk < 4; ++kk)
            c = __builtin_amdgcn_mfma_f32_32x32x16_bf16(
                    h2f[kk], *(const bf16x8*)&sW[640 + (n*4 + kk)*64 + lane], c, 0, 0, 0);
        float m;
        if (full) {
            m = fmaxf(fmaxf(fmaxf(c[0],c[1]), fmaxf(c[2],c[3])),
                      fmaxf(fmaxf(c[4],c[5]), fmaxf(c[6],c[7])));
            m = fmaxf(m, fmaxf(fmaxf(c[8],c[9]),  fmaxf(c[10],c[11])));
            m = fmaxf(m, fmaxf(fmaxf(c[12],c[13]), fmaxf(c[14],c[15])));
        } else {
            m = -INFINITY;
            #pragma unroll
            for (int reg = 0; reg < 16; ++reg) {
                int r = (reg & 3) + 8*(reg >> 2) + 4*hi;   // edge slot
                float v = (r < cnt) ? c[reg] : -INFINITY;
                m = fmaxf(m, v);
            }
        }
        m = fmaxf(m, __shfl_xor(m, 32));
        m += b3v[n];
        if (hi == 0) out[qq*128 + n*32 + (lane & 31)] = m;
    }
}

extern "C" void kernel_launch(void* const* d_in, const int* in_sizes, int n_in,
                              void* d_out, int out_size, void* d_ws, size_t ws_size,
                              hipStream_t stream) {
    const float* x     = (const float*)d_in[0];
    const float* pos   = (const float*)d_in[1];
    const int*   batch = (const int*)d_in[2];
    const float* W1    = (const float*)d_in[3];
    const float* b1    = (const float*)d_in[4];
    const float* W2    = (const float*)d_in[5];
    const float* b2    = (const float*)d_in[6];
    const float* W3    = (const float*)d_in[7];
    const float* b3    = (const float*)d_in[8];
    float* out = (float*)d_out;

    int* nbr  = (int*)d_ws;                                  // 16384*32 int  (2 MB)
    int* cnts = nbr + NTOT * KMAX;                           // 16384 int     (64 KB)
    float* xp = (float*)(cnts + NTOT);                       // 16384*8 f32   (512 KB)
    unsigned short* wfrag = (unsigned short*)(xp + NTOT*8);  // 14336 bf16    (28 KB)

    prep_kernel<<<2204, 512, 0, stream>>>(x, pos, batch, W1, b1, W2, b2, W3,
                                          nbr, cnts, xp, wfrag, out);
    mlp_kernel<<<NTOT / 4, 256, 0, stream>>>(wfrag, b3, xp, nbr, cnts, out);
}

// Round 10
// 36.754 us; speedup vs baseline: 1.1800x; 1.0460x over previous
//
#include <hip/hip_runtime.h>
#include <hip/hip_bf16.h>
#include <math.h>

#define NPC   2048          // points per cloud
#define NC    8             // clouds
#define NTOT  (NPC * NC)    // 16384
#define KMAX  32
#define R2    0.04f         // f32(0.04) — boundary-exact vs numpy's f64 compare

typedef short bf16x8  __attribute__((ext_vector_type(8)));
typedef float f32x16  __attribute__((ext_vector_type(16)));

// f32 -> bf16 round-to-nearest-even (finite values only)
__device__ __forceinline__ unsigned int f2bf(float f) {
    unsigned int u = __float_as_uint(f);
    return (u + 0x7FFFu + ((u >> 16) & 1u)) >> 16;
}

// packed f32x2 -> bf16x2 (RNE), src0 in LOW half (validated round 5)
__device__ __forceinline__ unsigned int pkbf(float a, float b) {
    unsigned int r;
    asm("v_cvt_pk_bf16_f32 %0, %1, %2" : "=v"(r) : "v"(a), "v"(b));
    return r;
}

// ---- k-permuted epilogue (validated round 8): relu+pack 8 consecutive acc regs -> operand frag ----
// Prep permutes the NEXT layer's weight k-rows by
// P(kk,hi,j) = (j&3) + 4*hi + 8*(2*(kk&1)+(j>>2)) + 32*(kk>>1)  == accumulator's natural row order.
__device__ __forceinline__ bf16x8 mk_frag(const f32x16& a, int off) {  // off: 0 or 8 (compile-time)
    int4 w;
    w.x = (int)pkbf(fmaxf(a[off+0],0.f), fmaxf(a[off+1],0.f));
    w.y = (int)pkbf(fmaxf(a[off+2],0.f), fmaxf(a[off+3],0.f));
    w.z = (int)pkbf(fmaxf(a[off+4],0.f), fmaxf(a[off+5],0.f));
    w.w = (int)pkbf(fmaxf(a[off+6],0.f), fmaxf(a[off+7],0.f));
    return __builtin_bit_cast(bf16x8, w);
}

// ============ kernel 1: LDS-staged nbr search + xp pack + weight frags + tail (round 9, validated) ============
__global__ __launch_bounds__(512) void prep_kernel(
    const float* __restrict__ x, const float* __restrict__ pos,
    const int* __restrict__ batch,
    const float* __restrict__ W1, const float* __restrict__ b1,
    const float* __restrict__ W2, const float* __restrict__ b2,
    const float* __restrict__ W3,
    int* __restrict__ nbr, int* __restrict__ cnts,
    float* __restrict__ xp, unsigned short* __restrict__ wf,
    float* __restrict__ out)
{
    __shared__ float4 sP[NPC];   // 32 KB: this cloud's positions (pad .w=0)

    int b = blockIdx.x, tid = threadIdx.x;
    if (b < 2048) {
        const int base = (b >> 8) << 11;      // cloud start (256 blocks per cloud)
        #pragma unroll
        for (int p = tid; p < NPC; p += 512) {
            sP[p] = make_float4(pos[3*(base+p)], pos[3*(base+p)+1], pos[3*(base+p)+2], 0.f);
        }
        __syncthreads();

        const int lane = tid & 63;
        const int q    = b * 8 + (tid >> 6);
        float qx = pos[3*q], qy = pos[3*q+1], qz = pos[3*q+2];
        int cnt = 0;
        for (int j0 = 0; j0 < NPC && cnt < KMAX; j0 += 256) {
            unsigned long long ms[4];
            bool vs[4];
            #pragma unroll
            for (int s = 0; s < 4; ++s) {
                float4 p = sP[j0 + s*64 + lane];          // ds_read_b128, imm offsets
                float dx = __fsub_rn(p.x, qx);
                float dy = __fsub_rn(p.y, qy);
                float dz = __fsub_rn(p.z, qz);
                float d2 = __fadd_rn(__fadd_rn(__fmul_rn(dx,dx), __fmul_rn(dy,dy)),
                                     __fmul_rn(dz,dz));
                vs[s] = d2 <= R2;
                ms[s] = __ballot(vs[s]);
            }
            #pragma unroll
            for (int s = 0; s < 4; ++s) {
                int before = (int)__popcll(ms[s] & ((1ull << lane) - 1ull));
                int slot = cnt + before;
                if (vs[s] && slot < KMAX) nbr[(q << 5) + slot] = base + j0 + s*64 + lane;
                cnt += (int)__popcll(ms[s]);
            }
        }
        if (lane == 0) cnts[q] = cnt < KMAX ? cnt : KMAX;
    } else if (b < 2080) {
        int i = (b - 2048) * 512 + tid;
        float4 v0 = {x[3*i], x[3*i+1], x[3*i+2], pos[3*i]};
        float4 v1 = {pos[3*i+1], pos[3*i+2], 0.f, 0.f};
        float4* dst = (float4*)(xp + 8 * i);
        dst[0] = v0; dst[1] = v1;
    } else if (b < 2108) {
        int g = (b - 2080) * 512 + tid;       // 0..14335
        if (g < 1024) {
            int j = g & 7, lane = (g >> 3) & 63, t = g >> 9;
            int k = (lane >> 5)*8 + j, ch = t*32 + (lane & 31);
            float v = (k < 6) ? W1[k*64 + ch] : (k == 6 ? b1[ch] : 0.f);
            wf[g] = (unsigned short)f2bf(v);
        } else if (g < 6144) {
            int g2 = g - 1024;
            int j = g2 & 7, lane = (g2 >> 3) & 63, f = g2 >> 9;
            int t = f / 5, kk = f % 5;
            int hi = lane >> 5, row = t*32 + (lane & 31);
            float v;
            if (kk < 4) {
                int k = (j & 3) + 4*hi + 8*(2*(kk & 1) + (j >> 2)) + 32*(kk >> 1);
                v = W2[k*64 + row];
            } else {
                v = (hi == 0 && j == 0) ? b2[row] : 0.f;   // bias row, matches `onef` B-frag
            }
            wf[g] = (unsigned short)f2bf(v);
        } else {
            int g3 = g - 6144;
            int j = g3 & 7, lane = (g3 >> 3) & 63, f = g3 >> 9;
            int n = f >> 2, kk = f & 3;
            int hi = lane >> 5, col = n*32 + (lane & 31);
            int k = (j & 3) + 4*hi + 8*(2*(kk & 1) + (j >> 2)) + 32*(kk >> 1);
            wf[g] = (unsigned short)f2bf(W3[k*128 + col]);
        }
    } else {
        int i = (b - 2108) * 512 + tid;
        if (i < NTOT*3) out[NTOT*128 + i] = pos[i];
        if (i < NTOT)   out[NTOT*131 + i] = (float)batch[i];
    }
}

// ============ kernel 2: fused MLP, all-MFMA, Q=2 queries INTERLEAVED per wave ============
// 4 waves/block, 8 queries/block, grid 2048. Every LDS weight-frag read feeds BOTH queries;
// every MFMA/VALU stage runs two independent dependency chains (ILP x2).
__global__ __launch_bounds__(256, 3) void mlp_kernel(
    const unsigned short* __restrict__ wf, const float* __restrict__ b3,
    const float* __restrict__ xp,
    const int* __restrict__ nbr, const int* __restrict__ cnts,
    float* __restrict__ out)
{
    __shared__ int4 sW[1664];   // 26624B: wg2a(640 int4) | wg3b(1024 int4)

    const int tid  = threadIdx.x;
    const int lane = tid & 63, wave = tid >> 6;
    const int e = lane & 31, hi = lane >> 5;

    const int q0 = __builtin_amdgcn_readfirstlane(blockIdx.x * 8 + wave * 2);
    const int q1 = q0 + 1;
    const int cnt0 = cnts[q0], cnt1 = cnts[q1];

    // ---- issue both queries' gathers up front (8 loads in flight) ----
    int jg0 = (e < cnt0) ? nbr[(q0 << 5) + e] : q0;
    int jg1 = (e < cnt1) ? nbr[(q1 << 5) + e] : q1;
    float4 a0 = ((const float4*)(xp + 8*jg0))[0], a1 = ((const float4*)(xp + 8*jg0))[1];
    float4 c0 = ((const float4*)(xp + 8*jg1))[0], c1 = ((const float4*)(xp + 8*jg1))[1];
    float p0x = xp[8*q0 + 3], p0y = xp[8*q0 + 4], p0z = xp[8*q0 + 5];
    float p1x = xp[8*q1 + 3], p1y = xp[8*q1 + 4], p1z = xp[8*q1 + 5];

    // layer1 W frags in registers (tiny, used first)
    bf16x8 wA1_0 = *(const bf16x8*)(wf + (0*64 + lane)*8);
    bf16x8 wA1_1 = *(const bf16x8*)(wf + (1*64 + lane)*8);

    float b3v[4];
    #pragma unroll
    for (int n = 0; n < 4; ++n) b3v[n] = b3[n*32 + e];

    // stage GEMM2/GEMM3 weight frags to LDS (once per block, amortized over 8 queries)
    const int4* wsrc = (const int4*)(wf + 1024);
    #pragma unroll
    for (int it = 0; it < 7; ++it) {
        int idx = it*256 + tid;
        if (idx < 1664) sW[idx] = wsrc[idx];
    }
    __syncthreads();

    const unsigned int one_w = pkbf(1.0f, 0.0f);
    int4 ow = {0,0,0,0};
    if (!hi) ow.x = (int)one_w;
    const bf16x8 onef = __builtin_bit_cast(bf16x8, ow);   // GEMM2 bias-row B-frag

    // ---- layer1 msg B-frags: k = [x0 x1 x2 r0 r1 r2 1 0 | 0...] ----
    int4 mw0, mw1;
    mw0.x = hi ? 0 : (int)pkbf(a0.x, a0.y);
    mw0.y = hi ? 0 : (int)pkbf(a0.z, a0.w - p0x);
    mw0.z = hi ? 0 : (int)pkbf(a1.x - p0y, a1.y - p0z);
    mw0.w = hi ? 0 : (int)one_w;
    mw1.x = hi ? 0 : (int)pkbf(c0.x, c0.y);
    mw1.y = hi ? 0 : (int)pkbf(c0.z, c0.w - p1x);
    mw1.z = hi ? 0 : (int)pkbf(c1.x - p1y, c1.y - p1z);
    mw1.w = hi ? 0 : (int)one_w;
    bf16x8 msg0 = __builtin_bit_cast(bf16x8, mw0);
    bf16x8 msg1 = __builtin_bit_cast(bf16x8, mw1);

    // ---- layer1 (swapped): C1^T[64 ch][32 e], K=16 — two independent chains ----
    f32x16 l0a = {}, l0b = {}, l1a = {}, l1b = {};
    l0a = __builtin_amdgcn_mfma_f32_32x32x16_bf16(wA1_0, msg0, l0a, 0, 0, 0);
    l1a = __builtin_amdgcn_mfma_f32_32x32x16_bf16(wA1_0, msg1, l1a, 0, 0, 0);
    l0b = __builtin_amdgcn_mfma_f32_32x32x16_bf16(wA1_1, msg0, l0b, 0, 0, 0);
    l1b = __builtin_amdgcn_mfma_f32_32x32x16_bf16(wA1_1, msg1, l1b, 0, 0, 0);
    bf16x8 h1f0[4], h1f1[4];
    h1f0[0] = mk_frag(l0a, 0); h1f0[1] = mk_frag(l0a, 8);
    h1f0[2] = mk_frag(l0b, 0); h1f0[3] = mk_frag(l0b, 8);
    h1f1[0] = mk_frag(l1a, 0); h1f1[1] = mk_frag(l1a, 8);
    h1f1[2] = mk_frag(l1b, 0); h1f1[3] = mk_frag(l1b, 8);

    // ---- GEMM2 (swapped): C2^T[64][32], K=80 — each frag read shared by both queries ----
    f32x16 g0a = {}, g0b = {}, g1a = {}, g1b = {};
    #pragma unroll
    for (int kk = 0; kk < 4; ++kk) {
        bf16x8 wa = *(const bf16x8*)&sW[(0*5 + kk)*64 + lane];
        bf16x8 wb = *(const bf16x8*)&sW[(1*5 + kk)*64 + lane];
        g0a = __builtin_amdgcn_mfma_f32_32x32x16_bf16(wa, h1f0[kk], g0a, 0, 0, 0);
        g1a = __builtin_amdgcn_mfma_f32_32x32x16_bf16(wa, h1f1[kk], g1a, 0, 0, 0);
        g0b = __builtin_amdgcn_mfma_f32_32x32x16_bf16(wb, h1f0[kk], g0b, 0, 0, 0);
        g1b = __builtin_amdgcn_mfma_f32_32x32x16_bf16(wb, h1f1[kk], g1b, 0, 0, 0);
    }
    {
        bf16x8 wa = *(const bf16x8*)&sW[(0*5 + 4)*64 + lane];
        bf16x8 wb = *(const bf16x8*)&sW[(1*5 + 4)*64 + lane];
        g0a = __builtin_amdgcn_mfma_f32_32x32x16_bf16(wa, onef, g0a, 0, 0, 0);
        g1a = __builtin_amdgcn_mfma_f32_32x32x16_bf16(wa, onef, g1a, 0, 0, 0);
        g0b = __builtin_amdgcn_mfma_f32_32x32x16_bf16(wb, onef, g0b, 0, 0, 0);
        g1b = __builtin_amdgcn_mfma_f32_32x32x16_bf16(wb, onef, g1b, 0, 0, 0);
    }
    bf16x8 h2f0[4], h2f1[4];
    h2f0[0] = mk_frag(g0a, 0); h2f0[1] = mk_frag(g0a, 8);
    h2f0[2] = mk_frag(g0b, 0); h2f0[3] = mk_frag(g0b, 8);
    h2f1[0] = mk_frag(g1a, 0); h2f1[1] = mk_frag(g1a, 8);
    h2f1[2] = mk_frag(g1b, 0); h2f1[3] = mk_frag(g1b, 8);

    // ---- GEMM3 (non-swapped): C[32 e][128 out] + fused max — frag reads shared ----
    const bool full0 = (cnt0 == 32), full1 = (cnt1 == 32);
    #pragma unroll
    for (int n = 0; n < 4; ++n) {
        f32x16 v0 = {}, v1 = {};
        #pragma unroll
        for (int kk = 0; kk < 4; ++kk) {
            bf16x8 bw = *(const bf16x8*)&sW[640 + (n*4 + kk)*64 + lane];
            v0 = __builtin_amdgcn_mfma_f32_32x32x16_bf16(h2f0[kk], bw, v0, 0, 0, 0);
            v1 = __builtin_amdgcn_mfma_f32_32x32x16_bf16(h2f1[kk], bw, v1, 0, 0, 0);
        }
        float m0, m1;
        if (full0) {
            m0 = fmaxf(fmaxf(fmaxf(v0[0],v0[1]), fmaxf(v0[2],v0[3])),
                       fmaxf(fmaxf(v0[4],v0[5]), fmaxf(v0[6],v0[7])));
            m0 = fmaxf(m0, fmaxf(fmaxf(v0[8],v0[9]),  fmaxf(v0[10],v0[11])));
            m0 = fmaxf(m0, fmaxf(fmaxf(v0[12],v0[13]), fmaxf(v0[14],v0[15])));
        } else {
            m0 = -INFINITY;
            #pragma unroll
            for (int reg = 0; reg < 16; ++reg) {
                int r = (reg & 3) + 8*(reg >> 2) + 4*hi;
                m0 = fmaxf(m0, (r < cnt0) ? v0[reg] : -INFINITY);
            }
        }
        if (full1) {
            m1 = fmaxf(fmaxf(fmaxf(v1[0],v1[1]), fmaxf(v1[2],v1[3])),
                       fmaxf(fmaxf(v1[4],v1[5]), fmaxf(v1[6],v1[7])));
            m1 = fmaxf(m1, fmaxf(fmaxf(v1[8],v1[9]),  fmaxf(v1[10],v1[11])));
            m1 = fmaxf(m1, fmaxf(fmaxf(v1[12],v1[13]), fmaxf(v1[14],v1[15])));
        } else {
            m1 = -INFINITY;
            #pragma unroll
            for (int reg = 0; reg < 16; ++reg) {
                int r = (reg & 3) + 8*(reg >> 2) + 4*hi;
                m1 = fmaxf(m1, (r < cnt1) ? v1[reg] : -INFINITY);
            }
        }
        m0 = fmaxf(m0, __shfl_xor(m0, 32)) + b3v[n];
        m1 = fmaxf(m1, __shfl_xor(m1, 32)) + b3v[n];
        if (hi == 0) {
            out[q0*128 + n*32 + e] = m0;
            out[q1*128 + n*32 + e] = m1;
        }
    }
}

extern "C" void kernel_launch(void* const* d_in, const int* in_sizes, int n_in,
                              void* d_out, int out_size, void* d_ws, size_t ws_size,
                              hipStream_t stream) {
    const float* x     = (const float*)d_in[0];
    const float* pos   = (const float*)d_in[1];
    const int*   batch = (const int*)d_in[2];
    const float* W1    = (const float*)d_in[3];
    const float* b1    = (const float*)d_in[4];
    const float* W2    = (const float*)d_in[5];
    const float* b2    = (const float*)d_in[6];
    const float* W3    = (const float*)d_in[7];
    const float* b3    = (const float*)d_in[8];
    float* out = (float*)d_out;

    int* nbr  = (int*)d_ws;                                  // 16384*32 int  (2 MB)
    int* cnts = nbr + NTOT * KMAX;                           // 16384 int     (64 KB)
    float* xp = (float*)(cnts + NTOT);                       // 16384*8 f32   (512 KB)
    unsigned short* wfrag = (unsigned short*)(xp + NTOT*8);  // 14336 bf16    (28 KB)

    prep_kernel<<<2204, 512, 0, stream>>>(x, pos, batch, W1, b1, W2, b2, W3,
                                          nbr, cnts, xp, wfrag, out);
    mlp_kernel<<<NTOT / 8, 256, 0, stream>>>(wfrag, b3, xp, nbr, cnts, out);
}